// Round 12
// baseline (275.224 us; speedup 1.0000x reference)
//
#include <hip/hip_runtime.h>
#include <hip/hip_fp16.h>
#include <cstdint>
#include <cstddef>

// SlotAttention, round 11.
//  - fused_k: ONE xh sweep per iteration, wave-autonomous (no barriers, no
//    LDS). Wave = 64 tokens; lane owns 8 dims; dots via fdot2 + shfl_xor
//    butterfly; softmax redundant per 32-group; u partials in 64 registers,
//    flushed once per wave (fp32). S partials per wave.
//  - attn_tr_k: coalesced [tok][8]fp16 -> [8][tok]fp32 de-interleave (once).
//  - xh_prep / convert_weights / slot_update proven (r6-r8); slot_update
//    phase-0 reads fp32 u_part (64 wave-chunks), S over 64 parts.

#define NTOK 4096
#define DDIM 256
#define NSLOT 8
#define NBATCH 32
#define NWV 64                  // waves per batch, 64 tokens each
#define SROWS (NBATCH * NSLOT)
#define NROWS (NBATCH * NTOK)
#define SCALE 0.0625f
#define LN_EPS_C 1e-5f
#define ATTN_EPS_C 1e-8f

typedef _Float16 f16x2 __attribute__((ext_vector_type(2)));
union U2H { unsigned u; f16x2 h; __half2 hh; };

__device__ __forceinline__ void wave_reduce2(float& s, float& ss) {
#pragma unroll
  for (int off = 32; off > 0; off >>= 1) {
    s  += __shfl_down(s, off, 64);
    ss += __shfl_down(ss, off, 64);
  }
}
__device__ __forceinline__ void wave_reduce2_xor(float& s, float& ss) {
#pragma unroll
  for (int off = 32; off > 0; off >>= 1) {
    s  += __shfl_xor(s, off, 64);
    ss += __shfl_xor(ss, off, 64);
  }
}

// transpose 6 weight matrices to fp16; plain-convert Wk to fp16 (r6 proven).
__global__ __launch_bounds__(256) void convert_weights_k(
    const float* __restrict__ Wq, const float* __restrict__ Wv,
    const float* __restrict__ Wih, const float* __restrict__ Whh,
    const float* __restrict__ W1, const float* __restrict__ W2,
    const float* __restrict__ Wk, __half* __restrict__ WqT,
    __half* __restrict__ WvT, __half* __restrict__ WihT,
    __half* __restrict__ WhhT, __half* __restrict__ W1T,
    __half* __restrict__ W2T, __half* __restrict__ Wk_h) {
  __shared__ float tile[32][33];
  int bz = blockIdx.x;
  int tx = threadIdx.x & 31, ty = threadIdx.x >> 5;
  if (bz >= 80) {
    int ro = (bz - 80) * 32, cd = blockIdx.y * 32;
#pragma unroll
    for (int p = 0; p < 32; p += 8)
      Wk_h[(size_t)(ro + ty + p) * DDIM + cd + tx] =
          __float2half(Wk[(size_t)(ro + ty + p) * DDIM + cd + tx]);
    return;
  }
  const float* in; __half* out; int O, bo;
  if (bz < 8)       { in = Wq;  out = WqT;  O = 256; bo = bz; }
  else if (bz < 16) { in = Wv;  out = WvT;  O = 256; bo = bz - 8; }
  else if (bz < 40) { in = Wih; out = WihT; O = 768; bo = bz - 16; }
  else if (bz < 64) { in = Whh; out = WhhT; O = 768; bo = bz - 40; }
  else if (bz < 72) { in = W1;  out = W1T;  O = 256; bo = bz - 64; }
  else              { in = W2;  out = W2T;  O = 256; bo = bz - 72; }
  int ro = bo * 32, cd = blockIdx.y * 32;
#pragma unroll
  for (int p = 0; p < 32; p += 8)
    tile[ty + p][tx] = in[(size_t)(ro + ty + p) * DDIM + cd + tx];
  __syncthreads();
#pragma unroll
  for (int p = 0; p < 32; p += 8)
    out[(size_t)(cd + ty + p) * O + ro + tx] = __float2half(tile[tx][ty + p]);
}

// streaming LN -> fp16. wave per row (64 lanes x float4 = 256 floats).
__global__ __launch_bounds__(256) void xh_prep_k(
    const float* __restrict__ X, const float* __restrict__ g,
    const float* __restrict__ be, __half* __restrict__ xh) {
  int row = blockIdx.x * 4 + (threadIdx.x >> 6);
  int lane = threadIdx.x & 63;
  float4 a = *(const float4*)(X + (size_t)row * DDIM + lane * 4);
  float s = a.x + a.y + a.z + a.w;
  float ss = a.x * a.x + a.y * a.y + a.z * a.z + a.w * a.w;
  wave_reduce2_xor(s, ss);
  float m = s * (1.f / DDIM);
  float rs = rsqrtf(ss * (1.f / DDIM) - m * m + LN_EPS_C);
  float4 gv = *(const float4*)(g + lane * 4);
  float4 bev = *(const float4*)(be + lane * 4);
  union { __half2 h[2]; uint2 u; } pk;
  pk.h[0] = __floats2half2_rn((a.x - m) * rs * gv.x + bev.x,
                              (a.y - m) * rs * gv.y + bev.y);
  pk.h[1] = __floats2half2_rn((a.z - m) * rs * gv.z + bev.z,
                              (a.w - m) * rs * gv.w + bev.w);
  *(uint2*)(xh + (size_t)row * DDIM + lane * 4) = pk.u;
}

// ONE-SWEEP fused token pass. Block = (b, 4-wave group); waves independent.
// Wave wv handles tokens [wv*64, wv*64+64). Lane: half = lane>>5 (token
// parity), r = lane&31 (dims r*8..r*8+8).
__global__ __launch_bounds__(256) void fused_k(
    const __half* __restrict__ xh, const float* __restrict__ qk,
    const float* __restrict__ qkb, float* __restrict__ u_part,
    float* __restrict__ S_part, __half* __restrict__ ae_buf, int write_ae) {
  int b = blockIdx.x, t = threadIdx.x;
  int wv = blockIdx.y * 4 + (t >> 6);
  int lane = t & 63, half = lane >> 5, r = lane & 31;
  // qk fragment (8 slots x 8 dims) as packed fp16
  f16x2 qk2[NSLOT][4];
#pragma unroll
  for (int i = 0; i < NSLOT; ++i) {
    const float* qr = qk + ((size_t)b * NSLOT + i) * DDIM + r * 8;
    float4 a = *(const float4*)qr;
    float4 c = *(const float4*)(qr + 4);
    qk2[i][0] = (f16x2){(_Float16)a.x, (_Float16)a.y};
    qk2[i][1] = (f16x2){(_Float16)a.z, (_Float16)a.w};
    qk2[i][2] = (f16x2){(_Float16)c.x, (_Float16)c.y};
    qk2[i][3] = (f16x2){(_Float16)c.z, (_Float16)c.w};
  }
  float qkb_r[NSLOT];
#pragma unroll
  for (int i = 0; i < NSLOT; ++i) qkb_r[i] = qkb[b * NSLOT + i];
  float uacc[NSLOT][8] = {};
  float sacc[NSLOT] = {};
  const __half* base = xh + ((size_t)b * NTOK + (size_t)wv * 64) * DDIM;
#pragma unroll 4
  for (int p = 0; p < 32; ++p) {
    int tok = p * 2 + half;
    uint4 v = *(const uint4*)(base + (size_t)tok * DDIM + r * 8);
    U2H x0, x1, x2, x3;
    x0.u = v.x; x1.u = v.y; x2.u = v.z; x3.u = v.w;
    float dot[NSLOT];
#pragma unroll
    for (int i = 0; i < NSLOT; ++i) {
      float s = 0.f;
      s = __builtin_amdgcn_fdot2(x0.h, qk2[i][0], s, false);
      s = __builtin_amdgcn_fdot2(x1.h, qk2[i][1], s, false);
      s = __builtin_amdgcn_fdot2(x2.h, qk2[i][2], s, false);
      s = __builtin_amdgcn_fdot2(x3.h, qk2[i][3], s, false);
      dot[i] = s;
    }
    // reduce over the 32-lane dim group (offsets stay within the half)
#pragma unroll
    for (int i = 0; i < NSLOT; ++i) {
      dot[i] += __shfl_xor(dot[i], 1, 64);
      dot[i] += __shfl_xor(dot[i], 2, 64);
      dot[i] += __shfl_xor(dot[i], 4, 64);
      dot[i] += __shfl_xor(dot[i], 8, 64);
      dot[i] += __shfl_xor(dot[i], 16, 64);
      dot[i] += qkb_r[i];
    }
    float mx = dot[0];
#pragma unroll
    for (int i = 1; i < NSLOT; ++i) mx = fmaxf(mx, dot[i]);
    float sum = 0.f;
    float ae[NSLOT];
#pragma unroll
    for (int i = 0; i < NSLOT; ++i) { ae[i] = __expf(dot[i] - mx); sum += ae[i]; }
    float inv = 1.f / sum;
#pragma unroll
    for (int i = 0; i < NSLOT; ++i) {
      ae[i] = fmaf(ae[i], inv, ATTN_EPS_C);
      sacc[i] += ae[i];
    }
    float2 f0 = __half22float2(x0.hh);
    float2 f1 = __half22float2(x1.hh);
    float2 f2 = __half22float2(x2.hh);
    float2 f3 = __half22float2(x3.hh);
    float xf[8] = {f0.x, f0.y, f1.x, f1.y, f2.x, f2.y, f3.x, f3.y};
#pragma unroll
    for (int i = 0; i < NSLOT; ++i)
#pragma unroll
      for (int d = 0; d < 8; ++d)
        uacc[i][d] = fmaf(ae[i], xf[d], uacc[i][d]);
    if (write_ae && r == 0) {
      union { __half2 h[4]; uint4 u; } pk;
#pragma unroll
      for (int i = 0; i < 4; ++i)
        pk.h[i] = __floats2half2_rn(ae[2 * i], ae[2 * i + 1]);
      *(uint4*)(ae_buf + ((size_t)b * NTOK + wv * 64 + tok) * NSLOT) = pk.u;
    }
  }
  // flush u: combine halves, store from half 0 (fp32)
#pragma unroll
  for (int i = 0; i < NSLOT; ++i)
#pragma unroll
    for (int d = 0; d < 8; ++d)
      uacc[i][d] += __shfl_down(uacc[i][d], 32, 64);
  if (half == 0) {
    float* up = u_part + (((size_t)b * NWV + wv) * NSLOT) * DDIM + r * 8;
#pragma unroll
    for (int i = 0; i < NSLOT; ++i) {
      float4 v0 = {uacc[i][0], uacc[i][1], uacc[i][2], uacc[i][3]};
      float4 v1 = {uacc[i][4], uacc[i][5], uacc[i][6], uacc[i][7]};
      *(float4*)(up + (size_t)i * DDIM) = v0;
      *(float4*)(up + (size_t)i * DDIM + 4) = v1;
    }
  }
#pragma unroll
  for (int i = 0; i < NSLOT; ++i) sacc[i] += __shfl_down(sacc[i], 32, 64);
  if (lane == 0) {
#pragma unroll
    for (int i = 0; i < NSLOT; ++i)
      S_part[((size_t)b * NWV + wv) * NSLOT + i] = sacc[i];
  }
}

// attn output: [b][tok][8] fp16 -> [b][8][tok] fp32, fully coalesced.
__global__ __launch_bounds__(256) void attn_tr_k(
    const __half* __restrict__ ae_buf, float* __restrict__ attn) {
  int b = blockIdx.x;
  int tok = blockIdx.y * 256 + threadIdx.x;
  uint4 v = *(const uint4*)(ae_buf + ((size_t)b * NTOK + tok) * NSLOT);
  const __half2* h = (const __half2*)&v;
#pragma unroll
  for (int i = 0; i < 4; ++i) {
    float2 f = __half22float2(h[i]);
    attn[((size_t)b * NSLOT + 2 * i) * NTOK + tok] = f.x - ATTN_EPS_C;
    attn[((size_t)b * NSLOT + 2 * i + 1) * NTOK + tok] = f.y - ATTN_EPS_C;
  }
}

// slot path, 1024 threads: o = t&255, ks = t>>8. fp16 weights. (r6-r8 proven;
// phase-0 reads fp32 u_part over 64 wave-chunks; S over 64 parts)
__global__ __launch_bounds__(1024) void slot_update_k(
    const float* __restrict__ u_part, const float* __restrict__ S_part,
    const float* __restrict__ slots_in, const __half* __restrict__ WvT,
    const float* __restrict__ bv, const __half* __restrict__ WihT,
    const __half* __restrict__ WhhT, const float* __restrict__ b_ih,
    const float* __restrict__ b_hh, const float* __restrict__ g_ff,
    const float* __restrict__ be_ff, const __half* __restrict__ W1T,
    const float* __restrict__ b1, const __half* __restrict__ W2T,
    const float* __restrict__ b2, const float* __restrict__ g_sl,
    const float* __restrict__ be_sl, const __half* __restrict__ WqT,
    const float* __restrict__ bq, const __half* __restrict__ Wk_h,
    const float* __restrict__ bk, const float* __restrict__ noise,
    const float* __restrict__ mu, const float* __restrict__ logsig,
    float* __restrict__ slots_out, float* __restrict__ qk,
    float* __restrict__ qkb_out, int init, int compute_qk) {
  __shared__ float red[4][6][DDIM];
  __shared__ float su[DDIM], sh[DDIM], supd[DDIM], v1[DDIM], v2[DDIM];
  __shared__ float scal[16];
  int r = blockIdx.x, t = threadIdx.x;
  int b = r >> 3, i = r & 7;
  int o = t & 255, ks = t >> 8;
  int lane = t & 63, wid = t >> 6;
  if (init) {
    if (ks == 0) {
      float ns = mu[o] + expf(logsig[o]) * noise[(size_t)r * DDIM + o];
      slots_out[(size_t)r * DDIM + o] = ns;
      v2[o] = ns;
    }
    __syncthreads();
  } else {
    {
      float up = 0.f;
      const float* upp =
          u_part + (((size_t)b * NWV + ks * 16) * NSLOT + i) * DDIM + o;
#pragma unroll
      for (int cc = 0; cc < 16; ++cc)
        up += upp[(size_t)cc * (NSLOT * DDIM)];
      red[ks][0][o] = up;
    }
    if (t < 64) {
      float sp = S_part[((size_t)b * NWV + t) * NSLOT + i];
#pragma unroll
      for (int off = 32; off > 0; off >>= 1) sp += __shfl_down(sp, off, 64);
      if (t == 0) scal[0] = sp;
    }
    if (ks == 0) sh[o] = slots_in[(size_t)r * DDIM + o];
    __syncthreads();
    if (ks == 0) {
      float invS = 1.f / scal[0];
      su[o] = (red[0][0][o] + red[1][0][o] + red[2][0][o] + red[3][0][o]) * invS;
    }
    __syncthreads();
    {
      float p = 0.f;
      const __half* wp = WvT + (size_t)(ks * 64) * DDIM + o;
#pragma unroll 8
      for (int dd = 0; dd < 64; ++dd)
        p = fmaf(su[ks * 64 + dd], __half2float(wp[(size_t)dd * DDIM]), p);
      red[ks][0][o] = p;
    }
    __syncthreads();
    if (ks == 0)
      supd[o] = bv[o] + red[0][0][o] + red[1][0][o] + red[2][0][o] + red[3][0][o];
    __syncthreads();
    {
      float p0 = 0, p1 = 0, p2 = 0, p3 = 0, p4 = 0, p5 = 0;
      const __half* pi = WihT + (size_t)(ks * 64) * (3 * DDIM) + o;
      const __half* ph = WhhT + (size_t)(ks * 64) * (3 * DDIM) + o;
#pragma unroll 4
      for (int dd = 0; dd < 64; ++dd) {
        float ud = supd[ks * 64 + dd], hd = sh[ks * 64 + dd];
        size_t off = (size_t)dd * (3 * DDIM);
        p0 = fmaf(ud, __half2float(pi[off]), p0);
        p1 = fmaf(ud, __half2float(pi[off + DDIM]), p1);
        p2 = fmaf(ud, __half2float(pi[off + 2 * DDIM]), p2);
        p3 = fmaf(hd, __half2float(ph[off]), p3);
        p4 = fmaf(hd, __half2float(ph[off + DDIM]), p4);
        p5 = fmaf(hd, __half2float(ph[off + 2 * DDIM]), p5);
      }
      red[ks][0][o] = p0; red[ks][1][o] = p1; red[ks][2][o] = p2;
      red[ks][3][o] = p3; red[ks][4][o] = p4; red[ks][5][o] = p5;
    }
    __syncthreads();
    if (ks == 0) {
      float air = b_ih[o] + red[0][0][o] + red[1][0][o] + red[2][0][o] + red[3][0][o];
      float aiz = b_ih[DDIM + o] + red[0][1][o] + red[1][1][o] + red[2][1][o] + red[3][1][o];
      float ain = b_ih[2 * DDIM + o] + red[0][2][o] + red[1][2][o] + red[2][2][o] + red[3][2][o];
      float ahr = b_hh[o] + red[0][3][o] + red[1][3][o] + red[2][3][o] + red[3][3][o];
      float ahz = b_hh[DDIM + o] + red[0][4][o] + red[1][4][o] + red[2][4][o] + red[3][4][o];
      float ahn = b_hh[2 * DDIM + o] + red[0][5][o] + red[1][5][o] + red[2][5][o] + red[3][5][o];
      float rg = 1.f / (1.f + expf(-(air + ahr)));
      float zg = 1.f / (1.f + expf(-(aiz + ahz)));
      float ng = tanhf(ain + rg * ahn);
      float nh = (1.f - zg) * ng + zg * sh[o];
      v1[o] = nh;
      float s2 = nh, ss2 = nh * nh;
      wave_reduce2(s2, ss2);
      if (lane == 0) { scal[wid] = s2; scal[4 + wid] = ss2; }
    }
    __syncthreads();
    if (ks == 0) {
      float sS = scal[0] + scal[1] + scal[2] + scal[3];
      float sQ = scal[4] + scal[5] + scal[6] + scal[7];
      float m = sS * (1.f / DDIM);
      float rs = rsqrtf(sQ * (1.f / DDIM) - m * m + LN_EPS_C);
      v2[o] = (v1[o] - m) * rs * g_ff[o] + be_ff[o];
    }
    __syncthreads();
    {
      float p = 0.f;
      const __half* wp = W1T + (size_t)(ks * 64) * DDIM + o;
#pragma unroll 8
      for (int dd = 0; dd < 64; ++dd)
        p = fmaf(v2[ks * 64 + dd], __half2float(wp[(size_t)dd * DDIM]), p);
      red[ks][0][o] = p;
    }
    __syncthreads();
    if (ks == 0)
      su[o] = fmaxf(b1[o] + red[0][0][o] + red[1][0][o] + red[2][0][o] + red[3][0][o], 0.f);
    __syncthreads();
    {
      float p = 0.f;
      const __half* wp = W2T + (size_t)(ks * 64) * DDIM + o;
#pragma unroll 8
      for (int dd = 0; dd < 64; ++dd)
        p = fmaf(su[ks * 64 + dd], __half2float(wp[(size_t)dd * DDIM]), p);
      red[ks][0][o] = p;
    }
    __syncthreads();
    if (ks == 0) {
      float out = v1[o] + b2[o] + red[0][0][o] + red[1][0][o] + red[2][0][o] + red[3][0][o];
      slots_out[(size_t)r * DDIM + o] = out;
      v2[o] = out;
    }
    __syncthreads();
  }
  if (!compute_qk) return;
  if (ks == 0) {
    float x = v2[o];
    float s2 = x, ss2 = x * x;
    wave_reduce2(s2, ss2);
    if (lane == 0) { scal[wid] = s2; scal[4 + wid] = ss2; }
  }
  __syncthreads();
  if (ks == 0) {
    float sS = scal[0] + scal[1] + scal[2] + scal[3];
    float sQ = scal[4] + scal[5] + scal[6] + scal[7];
    float m = sS * (1.f / DDIM);
    float rs = rsqrtf(sQ * (1.f / DDIM) - m * m + LN_EPS_C);
    su[o] = (v2[o] - m) * rs * g_sl[o] + be_sl[o];
  }
  __syncthreads();
  {
    float p = 0.f;
    const __half* wp = WqT + (size_t)(ks * 64) * DDIM + o;
#pragma unroll 8
    for (int dd = 0; dd < 64; ++dd)
      p = fmaf(su[ks * 64 + dd], __half2float(wp[(size_t)dd * DDIM]), p);
    red[ks][0][o] = p;
  }
  __syncthreads();
  if (ks == 0)
    sh[o] = bq[o] + red[0][0][o] + red[1][0][o] + red[2][0][o] + red[3][0][o];
  __syncthreads();
  {
    float p = 0.f;
    const __half* wp = Wk_h + (size_t)(ks * 64) * DDIM + o;
#pragma unroll 8
    for (int dd = 0; dd < 64; ++dd)
      p = fmaf(sh[ks * 64 + dd], __half2float(wp[(size_t)dd * DDIM]), p);
    red[ks][0][o] = p;
  }
  __syncthreads();
  if (ks == 0) {
    float qkv = SCALE * (red[0][0][o] + red[1][0][o] + red[2][0][o] + red[3][0][o]);
    qk[(size_t)r * DDIM + o] = qkv;
    float v0 = sh[o] * bk[o], d1 = 0.f;
    wave_reduce2(v0, d1);
    if (lane == 0) scal[wid] = v0;
  }
  __syncthreads();
  if (t == 0)
    qkb_out[r] = SCALE * (scal[0] + scal[1] + scal[2] + scal[3]);
}

extern "C" void kernel_launch(void* const* d_in, const int* in_sizes, int n_in,
                              void* d_out, int out_size, void* d_ws,
                              size_t ws_size, hipStream_t stream) {
  const float* inputs   = (const float*)d_in[0];
  const float* noise    = (const float*)d_in[1];
  const float* slots_mu = (const float*)d_in[2];
  const float* slots_ls = (const float*)d_in[3];
  const float* Wq   = (const float*)d_in[4];
  const float* bq   = (const float*)d_in[5];
  const float* Wk   = (const float*)d_in[6];
  const float* bk   = (const float*)d_in[7];
  const float* Wv   = (const float*)d_in[8];
  const float* bv   = (const float*)d_in[9];
  const float* W_ih = (const float*)d_in[10];
  const float* W_hh = (const float*)d_in[11];
  const float* b_ih = (const float*)d_in[12];
  const float* b_hh = (const float*)d_in[13];
  const float* W1   = (const float*)d_in[14];
  const float* b1   = (const float*)d_in[15];
  const float* W2   = (const float*)d_in[16];
  const float* b2   = (const float*)d_in[17];
  const float* g_in = (const float*)d_in[18];
  const float* be_in= (const float*)d_in[19];
  const float* g_sl = (const float*)d_in[20];
  const float* be_sl= (const float*)d_in[21];
  const float* g_ff = (const float*)d_in[22];
  const float* be_ff= (const float*)d_in[23];

  float* out_slots = (float*)d_out;                 // [32,8,256]
  float* out_attn  = (float*)d_out + SROWS * DDIM;  // [32,8,4096]

  float* w = (float*)d_ws;
  float* slots = w;  w += SROWS * DDIM;
  float* qk = w;     w += SROWS * DDIM;
  float* qkb = w;    w += SROWS;
  float* S_part = w; w += NBATCH * NWV * NSLOT;               // 16384
  float* u_part = w; w += (size_t)NBATCH * NWV * NSLOT * DDIM; // 16.8 MB fp32
  __half* h = (__half*)w;
  __half* xh = h;     h += (size_t)NROWS * DDIM;              // 67 MB
  __half* ae_buf = h; h += (size_t)NROWS * NSLOT;             // 2 MB
  __half* WqT_h = h;  h += DDIM * DDIM;
  __half* WvT_h = h;  h += DDIM * DDIM;
  __half* WihT_h = h; h += DDIM * 3 * DDIM;
  __half* WhhT_h = h; h += DDIM * 3 * DDIM;
  __half* W1T_h = h;  h += DDIM * DDIM;
  __half* W2T_h = h;  h += DDIM * DDIM;
  __half* Wk_h = h;   h += DDIM * DDIM;
  // total ws ~ 90 MB

  convert_weights_k<<<dim3(88, 8), 256, 0, stream>>>(
      Wq, Wv, W_ih, W_hh, W1, W2, Wk, WqT_h, WvT_h, WihT_h, WhhT_h, W1T_h,
      W2T_h, Wk_h);
  slot_update_k<<<SROWS, 1024, 0, stream>>>(
      u_part, S_part, slots, WvT_h, bv, WihT_h, WhhT_h, b_ih, b_hh, g_ff,
      be_ff, W1T_h, b1, W2T_h, b2, g_sl, be_sl, WqT_h, bq, Wk_h, bk, noise,
      slots_mu, slots_ls, slots, qk, qkb, 1, 1);
  xh_prep_k<<<NROWS / 4, 256, 0, stream>>>(inputs, g_in, be_in, xh);
  for (int it = 0; it < 3; ++it) {
    fused_k<<<dim3(NBATCH, 16), 256, 0, stream>>>(
        xh, qk, qkb, u_part, S_part, ae_buf, (it == 2) ? 1 : 0);
    float* sout = (it == 2) ? out_slots : slots;
    slot_update_k<<<SROWS, 1024, 0, stream>>>(
        u_part, S_part, slots, WvT_h, bv, WihT_h, WhhT_h, b_ih, b_hh, g_ff,
        be_ff, W1T_h, b1, W2T_h, b2, g_sl, be_sl, WqT_h, bq, Wk_h, bk, noise,
        slots_mu, slots_ls, sout, qk, qkb, 0, (it == 2) ? 0 : 1);
  }
  attn_tr_k<<<dim3(NBATCH, 16), 256, 0, stream>>>(ae_buf, out_attn);
}